// Round 6
// baseline (5938.868 us; speedup 1.0000x reference)
//
#include <hip/hip_runtime.h>
#include <hip/hip_cooperative_groups.h>

namespace cg = cooperative_groups;

#define Bdim 640
#define Hdim 768
#define PJdim 256
#define Tdim 160
#define NSTEP (Tdim + 2)

typedef _Float16 half8 __attribute__((ext_vector_type(8)));
typedef float floatx16 __attribute__((ext_vector_type(16)));

// ---------------- workspace layout (fragment-ordered fp16 images) ----------------
// hF:    [l3][bt2 5][kcH16][rt4][512]   projected state, MFMA-A-frag order (1 frag = 512 halfs)
// mbufF: [l3][bt2 5][kc48][rt4][512]    gate->proj handoff, A-frag order
// xF:    [t160][bt2 5][kcx4][rt4][512]  input cols 256..319 of layer-0 A ([h|x|pad] order)
// Wfrag: [l*12+ht][kc32][wv8][512]      gate weights, B-frag order (l0: kc<20 used)
// Pfrag: [l][cq4][kc48][cg2][512]       proj weights, B-frag order
// cfb:   fallback c-state
constexpr size_t HF_HALFS = 3ull * 5 * 16 * 4 * 512;     //   491,520
constexpr size_t MB_HALFS = 3ull * 5 * 48 * 4 * 512;     // 1,474,560
constexpr size_t XF_HALFS = 160ull * 5 * 4 * 4 * 512;    // 6,553,600
constexpr size_t WF_HALFS = 36ull * 32 * 8 * 512;        // 4,718,592
constexpr size_t PF_HALFS = 3ull * 4 * 48 * 2 * 512;     //   589,824
constexpr size_t HF_OFF  = 0;
constexpr size_t MB_OFF  = HF_HALFS * 2;
constexpr size_t XF_OFF  = MB_OFF + MB_HALFS * 2;
constexpr size_t WF_OFF  = XF_OFF + XF_HALFS * 2;
constexpr size_t PF_OFF  = WF_OFF + WF_HALFS * 2;
constexpr size_t CFB_OFF = PF_OFF + PF_HALFS * 2;
constexpr size_t CFB_BYTES = 180ull * 512 * 16 * 4;      // 5,898,240

__device__ __forceinline__ float sigm(float v) { return 1.0f / (1.0f + __expf(-v)); }
__device__ __forceinline__ float tanh_fast(float v) { return 2.0f / (1.0f + __expf(-2.0f * v)) - 1.0f; }

// ---------------- one-time repack into fragment-ordered images ----------------
__global__ void repack_kernel(const float* __restrict__ x,
                              const float* __restrict__ W0, const float* __restrict__ W1,
                              const float* __restrict__ W2, const float* __restrict__ P0,
                              const float* __restrict__ P1, const float* __restrict__ P2,
                              _Float16* __restrict__ Wfrag, _Float16* __restrict__ Pfrag,
                              _Float16* __restrict__ xF)
{
    size_t idx = (size_t)blockIdx.x * 256 + threadIdx.x;
    if (idx < WF_HALFS) {
        int slab = (int)(idx >> 17);                 // /131072
        int l = slab / 12, ht = slab % 12;
        int r = (int)(idx & 131071);
        int kc = r >> 12;                            // /4096
        int wvp = (r >> 9) & 7;
        int u = r & 511;
        int lane = u >> 3, e = u & 7;
        int g = wvp >> 1, hh = wvp & 1;
        int col = g * Hdim + ht * 64 + hh * 32 + (lane & 31);
        int a = kc * 16 + (lane >> 5) * 8 + e;       // A-column index
        float v = 0.0f;
        if (l == 0) {
            // layer-0 A order: [h_own(256) | x(40) | pad]; W0 rows: 0..39 x, 40..295 h
            if (a < 256)      v = W0[(size_t)(40 + a) * 3072 + col];
            else if (a < 296) v = W0[(size_t)(a - 256) * 3072 + col];
        } else if (a < 512) {
            const float* W = (l == 1) ? W1 : W2;
            v = W[(size_t)a * 3072 + col];
        }
        Wfrag[idx] = (_Float16)v;
    } else if (idx < WF_HALFS + PF_HALFS) {
        size_t i = idx - WF_HALFS;
        int l = (int)(i / 196608);
        int r = (int)(i % 196608);
        int cq = r / 49152;
        int r2 = r % 49152;
        int kc = r2 / 1024;
        int cgp = (r2 >> 9) & 1;
        int u = r2 & 511;
        int lane = u >> 3, e = u & 7;
        int pj = cq * 64 + cgp * 32 + (lane & 31);
        int k = kc * 16 + (lane >> 5) * 8 + e;
        const float* P = (l == 0) ? P0 : (l == 1) ? P1 : P2;
        Pfrag[i] = (_Float16)P[(size_t)k * PJdim + pj];
    } else if (idx < WF_HALFS + PF_HALFS + XF_HALFS) {
        size_t i = idx - WF_HALFS - PF_HALFS;
        int t = (int)(i / 40960);
        int r = (int)(i % 40960);
        int bt2 = r / 8192;
        int r2 = r % 8192;
        int kcx = r2 / 2048;
        int rt = (r2 >> 9) & 3;
        int u = r2 & 511;
        int lane = u >> 3, e = u & 7;
        int row = bt2 * 128 + rt * 32 + (lane & 31);
        int xcol = kcx * 16 + (lane >> 5) * 8 + e;   // a - 256
        float v = (xcol < 40) ? x[((size_t)t * Bdim + row) * 40 + xcol] : 0.0f;
        xF[i] = (_Float16)v;
    }
}

// ---------------- granule-staged GEMM cores (fully unrolled, 1 barrier/granule) ----------
template <int G>
__device__ __forceinline__ void gate_gemm(const uint4* const (&gs)[8], const half8 (&Breg)[32],
                                          floatx16 (&acc)[4], _Float16* Abuf, int tid, int lane)
{
    {
        uint4 v0 = gs[0][tid], v1 = gs[0][tid + 512];
        uint4* d = (uint4*)Abuf;
        d[tid] = v0; d[tid + 512] = v1;
        __syncthreads();
    }
#pragma unroll
    for (int g = 0; g < G; ++g) {
        uint4 p0, p1;
        const bool pf = (g + 1 < G);
        if (pf) { p0 = gs[g + 1][tid]; p1 = gs[g + 1][tid + 512]; }
        const _Float16* base = Abuf + (g & 1) * 8192;
#pragma unroll
        for (int c4 = 0; c4 < 4; ++c4) {
#pragma unroll
            for (int rt = 0; rt < 4; ++rt) {
                half8 a = *(const half8*)(base + (c4 * 4 + rt) * 512 + lane * 8);
                acc[rt] = __builtin_amdgcn_mfma_f32_32x32x16_f16(a, Breg[g * 4 + c4], acc[rt], 0, 0, 0);
            }
        }
        if (pf) {
            uint4* d = (uint4*)(Abuf + ((g + 1) & 1) * 8192);
            d[tid] = p0; d[tid + 512] = p1;
        }
        __syncthreads();
    }
}

__device__ __forceinline__ void proj_gemm(const uint4* const (&gs)[12], const half8 (&Preg)[48],
                                          floatx16& pacc, _Float16* Abuf, int tid, int lane, int rh)
{
    {
        uint4 v0 = gs[0][tid], v1 = gs[0][tid + 512];
        uint4* d = (uint4*)Abuf;
        d[tid] = v0; d[tid + 512] = v1;
        __syncthreads();
    }
#pragma unroll
    for (int g = 0; g < 12; ++g) {
        uint4 p0, p1;
        const bool pf = (g + 1 < 12);
        if (pf) { p0 = gs[g + 1][tid]; p1 = gs[g + 1][tid + 512]; }
        const _Float16* base = Abuf + (g & 1) * 8192;
#pragma unroll
        for (int c4 = 0; c4 < 4; ++c4) {
            half8 a = *(const half8*)(base + (c4 * 4 + rh) * 512 + lane * 8);
            pacc = __builtin_amdgcn_mfma_f32_32x32x16_f16(a, Preg[g * 4 + c4], pacc, 0, 0, 0);
        }
        if (pf) {
            uint4* d = (uint4*)(Abuf + ((g + 1) & 1) * 8192);
            d[tid] = p0; d[tid + 512] = p1;
        }
        __syncthreads();
    }
}

// ---------------- one gate cell-step: GEMM + elementwise + m flush ----------------
__device__ __forceinline__ void gate_run(int l, int ht, int bt2, int t,
                                         const half8 (&Breg)[32], float bv, float (&c)[8][2],
                                         const _Float16* __restrict__ hF,
                                         const _Float16* __restrict__ xF,
                                         _Float16* __restrict__ mbufF,
                                         char* smem, int tid)
{
    const int wv = tid >> 6, lane = tid & 63;
    const int g = wv >> 1, hh = wv & 1;
    _Float16* Abuf = (_Float16*)smem;

    floatx16 acc[4];
#pragma unroll
    for (int rt = 0; rt < 4; ++rt)
#pragma unroll
        for (int e = 0; e < 16; ++e) acc[rt][e] = 0.f;

    const uint4* gs[8];
    if (l == 0) {
        const _Float16* own = hF + (size_t)bt2 * 32768;
#pragma unroll
        for (int g2 = 0; g2 < 4; ++g2) gs[g2] = (const uint4*)(own + g2 * 8192);
        gs[4] = (const uint4*)(xF + ((size_t)t * 5 + bt2) * 8192);
        gs[5] = gs[6] = gs[7] = gs[4];
        gate_gemm<5>(gs, Breg, acc, Abuf, tid, lane);
    } else {
        const _Float16* lo = hF + ((size_t)(l - 1) * 5 + bt2) * 32768;
        const _Float16* hi = hF + ((size_t)l * 5 + bt2) * 32768;
#pragma unroll
        for (int g2 = 0; g2 < 4; ++g2) {
            gs[g2] = (const uint4*)(lo + g2 * 8192);
            gs[4 + g2] = (const uint4*)(hi + g2 * 8192);
        }
        gate_gemm<8>(gs, Breg, acc, Abuf, tid, lane);
    }

    // elementwise: z via LDS (aliases dead Abuf), 8 passes of 16 rows, c in VGPRs
    float* zst = (float*)smem;                    // 16 KB
    _Float16* Mlds = (_Float16*)(smem + 16384);   // 16 KB, frag-ordered m tile
    const int gcol = g * 64 + hh * 32 + (lane & 31);
    const int trow = tid >> 5, uu = tid & 31, hc0 = 2 * uu;
#pragma unroll
    for (int p = 0; p < 8; ++p) {
#pragma unroll
        for (int rr = 0; rr < 8; ++rr) {
            int r16 = (rr & 3) + ((rr >> 2) << 3) + ((lane >> 5) << 2);
            zst[r16 * 256 + gcol] = acc[p >> 1][(p & 1) * 8 + rr] + bv;
        }
        __syncthreads();
        unsigned pk = 0;
#pragma unroll
        for (int jj = 0; jj < 2; ++jj) {
            int hc = hc0 + jj;
            float zi = zst[trow * 256 + hc];
            float zj = zst[trow * 256 + 64 + hc];
            float zf = zst[trow * 256 + 128 + hc];
            float zo = zst[trow * 256 + 192 + hc];
            float cn = sigm(zf) * c[p][jj] + sigm(zi) * tanh_fast(zj);
            c[p][jj] = cn;
            _Float16 mh = (_Float16)(sigm(zo) * tanh_fast(cn));
            unsigned short us = *(unsigned short*)&mh;
            pk |= ((unsigned)us) << (16 * jj);
        }
        {
            int f = (p >> 1) * 4 + (hc0 >> 4);
            int lane32 = (p & 1) * 16 + trow + 32 * ((hc0 >> 3) & 1);
            *(unsigned*)(Mlds + f * 512 + lane32 * 8 + (hc0 & 7)) = pk;
        }
        __syncthreads();
    }
    // coalesced flush: Mlds (frag order) -> mbufF
    {
        int f = tid >> 5, o = (tid & 31) * 16;
        uint4 w0 = *(const uint4*)(Mlds + f * 512 + o);
        uint4 w1 = *(const uint4*)(Mlds + f * 512 + o + 8);
        _Float16* dst = mbufF + ((((size_t)l * 5 + bt2) * 48 + ht * 4 + (f & 3)) * 4 + (f >> 2)) * 512 + o;
        *(uint4*)dst = w0;
        *(uint4*)(dst + 8) = w1;
    }
}

// ---------------- one proj step: GEMM + frag-ordered h flush ----------------
__device__ __forceinline__ void proj_run(int l, int cq, int bt2, const half8 (&Preg)[48],
                                         const _Float16* __restrict__ mbufF,
                                         _Float16* __restrict__ hF,
                                         char* smem, int tid)
{
    const int wv = tid >> 6, lane = tid & 63;
    const int rh = wv >> 1, cgp = wv & 1;
    _Float16* Abuf = (_Float16*)smem;

    floatx16 pacc;
#pragma unroll
    for (int e = 0; e < 16; ++e) pacc[e] = 0.f;

    const _Float16* mslice = mbufF + ((size_t)l * 5 + bt2) * 98304;
    const uint4* gs[12];
#pragma unroll
    for (int g2 = 0; g2 < 12; ++g2) gs[g2] = (const uint4*)(mslice + g2 * 8192);
    proj_gemm(gs, Preg, pacc, Abuf, tid, lane, rh);

    _Float16* Hlds = (_Float16*)smem;             // 16 frags = 16 KB, aliases dead Abuf
    const int col32 = lane & 31;
    const int fH = (cgp * 2 + (col32 >> 4)) * 4 + rh;
    const int lane32 = 32 * ((col32 >> 3) & 1);
    const int e0 = col32 & 7;
#pragma unroll
    for (int q = 0; q < 4; ++q)
#pragma unroll
        for (int i = 0; i < 4; ++i) {
            int row32 = i + 8 * q + 4 * (lane >> 5);
            Hlds[fH * 512 + (row32 + lane32) * 8 + e0] = (_Float16)pacc[q * 4 + i];
        }
    __syncthreads();
    // BUGFIX R5->R6: flush ALL 16 fragments (was f = tid>>6, only 8 frags = half of h)
    {
        int f = tid >> 5, o = (tid & 31) * 16;
        uint4 w0 = *(const uint4*)(Hlds + f * 512 + o);
        uint4 w1 = *(const uint4*)(Hlds + f * 512 + o + 8);
        _Float16* dst = hF + ((((size_t)l * 5 + bt2) * 16 + cq * 4 + (f >> 2)) * 4 + (f & 3)) * 512 + o;
        *(uint4*)dst = w0;
        *(uint4*)(dst + 8) = w1;
    }
    __syncthreads();
}

__device__ __forceinline__ void finalize_row(const _Float16* __restrict__ hF,
                                             float* __restrict__ out, int row, int lane)
{
    int bt2 = row >> 7, rt = (row >> 5) & 3, r32 = row & 31;
    int kcH = lane >> 2;
    int l32 = r32 + 32 * ((lane >> 1) & 1);
    int e0 = (lane & 1) * 4;
    const _Float16* p = hF + ((((size_t)10 + bt2) * 16 + kcH) * 4 + rt) * 512 + l32 * 8 + e0;
    float v0 = (float)p[0], v1 = (float)p[1], v2 = (float)p[2], v3 = (float)p[3];
    float ss = v0 * v0 + v1 * v1 + v2 * v2 + v3 * v3;
#pragma unroll
    for (int o = 32; o > 0; o >>= 1) ss += __shfl_xor(ss, o, 64);
    float rs = rsqrtf(fmaxf(ss, 1e-12f));
    float4 o4;
    o4.x = v0 * rs; o4.y = v1 * rs; o4.z = v2 * rs; o4.w = v3 * rs;
    *(float4*)(out + (size_t)row * PJdim + lane * 4) = o4;
}

// ---------------- persistent cooperative kernel ----------------
__global__ __launch_bounds__(512, 1)
void lstm_persist(const _Float16* __restrict__ xF, const _Float16* __restrict__ Wfrag,
                  const _Float16* __restrict__ Pfrag,
                  const float* __restrict__ bias0, const float* __restrict__ bias1,
                  const float* __restrict__ bias2,
                  _Float16* __restrict__ hF, _Float16* __restrict__ mbufF,
                  float* __restrict__ out)
{
    cg::grid_group grid = cg::this_grid();
    __shared__ __align__(16) char smem[32768];
    const int tid = threadIdx.x, bid = blockIdx.x;
    const int wv = tid >> 6, lane = tid & 63;
    const int xc = bid & 7, j = bid >> 3;

    // XCD-grouped roles: group grp=(l,bt2) pinned to one XCD; 12 gate + 4 proj blocks/group
    int role = 0, l = 0, ht = 0, bt2 = 0, cq = 0;
    if (j < 24) {
        int grp = xc + 8 * (j / 12);
        if (grp < 15) { role = 1; l = grp / 5; bt2 = grp % 5; ht = j % 12; }
    } else {
        int grp = (j < 28) ? xc : xc + 8;
        if (grp < 15) { role = 2; l = grp / 5; bt2 = grp % 5; cq = (j < 28) ? (j - 24) : (j - 28); }
    }

    if (role == 1) {
        half8 Breg[32];
        const _Float16* wslab = Wfrag + (size_t)(l * 12 + ht) * 131072;
        const int nkc = (l == 0) ? 20 : 32;
#pragma unroll
        for (int kc = 0; kc < 32; ++kc)
            if (kc < nkc) Breg[kc] = *(const half8*)(wslab + (kc * 8 + wv) * 512 + lane * 8);
        const float* bias = (l == 0) ? bias0 : (l == 1) ? bias1 : bias2;
        const int g = wv >> 1, hh = wv & 1;
        const float bv = bias[g * Hdim + ht * 64 + hh * 32 + (lane & 31)] + ((g == 2) ? 1.0f : 0.0f);
        float c[8][2];
#pragma unroll
        for (int p = 0; p < 8; ++p) { c[p][0] = 0.f; c[p][1] = 0.f; }
        for (int s = 0; s < NSTEP; ++s) {
            const int t = s - l;
            if (t >= 0 && t < Tdim)
                gate_run(l, ht, bt2, t, Breg, bv, c, hF, xF, mbufF, smem, tid);
            grid.sync();
            grid.sync();
        }
    } else if (role == 2) {
        half8 Preg[48];
        const _Float16* pslab = Pfrag + ((size_t)l * 4 + cq) * 49152;
#pragma unroll
        for (int kc = 0; kc < 48; ++kc)
            Preg[kc] = *(const half8*)(pslab + (kc * 2 + (wv & 1)) * 512 + lane * 8);
        for (int s = 0; s < NSTEP; ++s) {
            grid.sync();
            const int t = s - l;
            if (t >= 0 && t < Tdim)
                proj_run(l, cq, bt2, Preg, mbufF, hF, smem, tid);
            grid.sync();
        }
    } else {
        for (int s = 0; s < NSTEP; ++s) { grid.sync(); grid.sync(); }
    }

    if (bid < 80) finalize_row(hF, out, bid * 8 + wv, lane);
}

// ---------------- fallback path: per-step kernels, c in global ----------------
__global__ __launch_bounds__(512, 1)
void gate_fb(const _Float16* __restrict__ xF, const _Float16* __restrict__ Wfrag,
             const float* __restrict__ bias0, const float* __restrict__ bias1,
             const float* __restrict__ bias2,
             _Float16* __restrict__ hF, _Float16* __restrict__ mbufF,
             float* __restrict__ cfb, int s)
{
    __shared__ __align__(16) char smem[32768];
    const int tid = threadIdx.x, bid = blockIdx.x;
    const int l = bid / 60, r = bid % 60, ht = r / 5, bt2 = r % 5;
    const int t = s - l;
    if (t < 0 || t >= Tdim) return;
    const int wv = tid >> 6, lane = tid & 63;
    half8 Breg[32];
    const _Float16* wslab = Wfrag + (size_t)(l * 12 + ht) * 131072;
    const int nkc = (l == 0) ? 20 : 32;
#pragma unroll
    for (int kc = 0; kc < 32; ++kc)
        if (kc < nkc) Breg[kc] = *(const half8*)(wslab + (kc * 8 + wv) * 512 + lane * 8);
    const float* bias = (l == 0) ? bias0 : (l == 1) ? bias1 : bias2;
    const int g = wv >> 1, hh = wv & 1;
    const float bv = bias[g * Hdim + ht * 64 + hh * 32 + (lane & 31)] + ((g == 2) ? 1.0f : 0.0f);
    float c[8][2];
    size_t cb = ((size_t)bid * 512 + tid) * 16;
#pragma unroll
    for (int p = 0; p < 8; ++p) { c[p][0] = cfb[cb + p * 2]; c[p][1] = cfb[cb + p * 2 + 1]; }
    gate_run(l, ht, bt2, t, Breg, bv, c, hF, xF, mbufF, smem, tid);
#pragma unroll
    for (int p = 0; p < 8; ++p) { cfb[cb + p * 2] = c[p][0]; cfb[cb + p * 2 + 1] = c[p][1]; }
}

__global__ __launch_bounds__(512, 1)
void proj_fb(const _Float16* __restrict__ Pfrag, const _Float16* __restrict__ mbufF,
             _Float16* __restrict__ hF, int s)
{
    __shared__ __align__(16) char smem[32768];
    const int tid = threadIdx.x, bid = blockIdx.x;
    const int l = bid / 20, r = bid % 20, cq = r / 5, bt2 = r % 5;
    const int t = s - l;
    if (t < 0 || t >= Tdim) return;
    const int wv = tid >> 6, lane = tid & 63;
    half8 Preg[48];
    const _Float16* pslab = Pfrag + ((size_t)l * 4 + cq) * 49152;
#pragma unroll
    for (int kc = 0; kc < 48; ++kc)
        Preg[kc] = *(const half8*)(pslab + (kc * 2 + (wv & 1)) * 512 + lane * 8);
    proj_run(l, cq, bt2, Preg, mbufF, hF, smem, tid);
}

__global__ __launch_bounds__(512, 1)
void fin_fb(const _Float16* __restrict__ hF, float* __restrict__ out)
{
    finalize_row(hF, out, blockIdx.x * 8 + (threadIdx.x >> 6), threadIdx.x & 63);
}

extern "C" void kernel_launch(void* const* d_in, const int* in_sizes, int n_in,
                              void* d_out, int out_size, void* d_ws, size_t ws_size,
                              hipStream_t stream)
{
    (void)in_sizes; (void)n_in; (void)out_size; (void)ws_size;
    const float* x  = (const float*)d_in[0];
    const float* W0 = (const float*)d_in[1];
    const float* b0 = (const float*)d_in[2];
    const float* P0 = (const float*)d_in[3];
    const float* W1 = (const float*)d_in[4];
    const float* b1 = (const float*)d_in[5];
    const float* P1 = (const float*)d_in[6];
    const float* W2 = (const float*)d_in[7];
    const float* b2 = (const float*)d_in[8];
    const float* P2 = (const float*)d_in[9];

    char* ws = (char*)d_ws;
    _Float16* hF    = (_Float16*)(ws + HF_OFF);
    _Float16* mbufF = (_Float16*)(ws + MB_OFF);
    _Float16* xF    = (_Float16*)(ws + XF_OFF);
    _Float16* Wfrag = (_Float16*)(ws + WF_OFF);
    _Float16* Pfrag = (_Float16*)(ws + PF_OFF);
    float*    cfb   = (float*)(ws + CFB_OFF);
    float*    outp  = (float*)d_out;

    hipMemsetAsync(hF, 0, HF_HALFS * 2, stream);
    hipMemsetAsync(cfb, 0, CFB_BYTES, stream);

    {
        constexpr size_t total = WF_HALFS + PF_HALFS + XF_HALFS;
        int grid = (int)((total + 255) / 256);
        repack_kernel<<<grid, 256, 0, stream>>>(x, W0, W1, W2, P0, P1, P2, Wfrag, Pfrag, xF);
    }

    int occ = 0;
    hipError_t oe = hipOccupancyMaxActiveBlocksPerMultiprocessor(&occ, lstm_persist, 512, 0);
    bool coop = (oe == hipSuccess && occ >= 1);
    if (coop) {
        void* args[] = { (void*)&xF, (void*)&Wfrag, (void*)&Pfrag,
                         (void*)&b0, (void*)&b1, (void*)&b2,
                         (void*)&hF, (void*)&mbufF, (void*)&outp };
        hipError_t le = hipLaunchCooperativeKernel((const void*)lstm_persist,
                                                   dim3(256), dim3(512), args, 0, stream);
        if (le != hipSuccess) { (void)hipGetLastError(); coop = false; }
    }
    if (!coop) {
        for (int s = 0; s < NSTEP; ++s) {
            gate_fb<<<180, 512, 0, stream>>>(xF, Wfrag, b0, b1, b2, hF, mbufF, cfb, s);
            proj_fb<<<60, 512, 0, stream>>>(Pfrag, mbufF, hF, s);
        }
        fin_fb<<<80, 512, 0, stream>>>(hF, outp);
    }
}

// Round 7
// 5334.249 us; speedup vs baseline: 1.1133x; 1.1133x over previous
//
#include <hip/hip_runtime.h>
#include <hip/hip_cooperative_groups.h>

namespace cg = cooperative_groups;

#define Bdim 640
#define Hdim 768
#define PJdim 256
#define Tdim 160
#define NSTEP (Tdim + 2)

typedef _Float16 half8 __attribute__((ext_vector_type(8)));
typedef float floatx16 __attribute__((ext_vector_type(16)));

// ---------------- workspace layout ----------------
// cnt:   240 sync counters, 64B apart (mCnt: (l*5+bt2)*12+ht ; projCnt: 180+(l*5+bt2)*4+cq)
// hF:    [par2][l3][bt2 5][kcH16][rt4][512]  projected state, A-frag order
// mbufF: [par2][l3][bt2 5][kc48][rt4][512]   gate->proj handoff, A-frag order
// xF:    [t160][bt2 5][kcx4][rt4][512]       layer-0 x granule ([h|x|pad] A order)
// Wfrag: [l*12+ht][kc32][wv8][512]           gate weights, B-frag order (l0: kc<20)
// Pfrag: [l][cq4][kc48][cg2][512]            proj weights, B-frag order
#define HFP 491520u
#define MBP 1474560u
constexpr size_t CNT_OFF = 0;                               // 256*64 = 16384 B
constexpr size_t HF_OFF  = 16384;
constexpr size_t MB_OFF  = HF_OFF + 2ull * HFP * 2;         //  1,982,464
constexpr size_t XF_OFF  = MB_OFF + 2ull * MBP * 2;         //  7,880,704
constexpr size_t XF_HALFS = 160ull * 5 * 4 * 4 * 512;       //  6,553,600
constexpr size_t WF_OFF  = XF_OFF + XF_HALFS * 2;           // 20,987,904
constexpr size_t WF_HALFS = 36ull * 32 * 8 * 512;           //  4,718,592
constexpr size_t PF_OFF  = WF_OFF + WF_HALFS * 2;           // 30,425,088
constexpr size_t PF_HALFS = 3ull * 4 * 48 * 2 * 512;        //    589,824
constexpr size_t CFB_OFF = PF_OFF + PF_HALFS * 2;           // 31,604,736
constexpr size_t CFB_BYTES = 180ull * 512 * 16 * 4;         //  5,898,240

__device__ __forceinline__ float sigm(float v) { return 1.0f / (1.0f + __expf(-v)); }
__device__ __forceinline__ float tanh_fast(float v) { return 2.0f / (1.0f + __expf(-2.0f * v)) - 1.0f; }

__device__ __forceinline__ void waitGE(int* p, int tgt) {
    while (__hip_atomic_load(p, __ATOMIC_ACQUIRE, __HIP_MEMORY_SCOPE_AGENT) < tgt)
        __builtin_amdgcn_s_sleep(1);
}
__device__ __forceinline__ void signal1(int* p) {
    __hip_atomic_fetch_add(p, 1, __ATOMIC_RELEASE, __HIP_MEMORY_SCOPE_AGENT);
}

// ---------------- one-time repack into fragment-ordered images ----------------
__global__ void repack_kernel(const float* __restrict__ x,
                              const float* __restrict__ W0, const float* __restrict__ W1,
                              const float* __restrict__ W2, const float* __restrict__ P0,
                              const float* __restrict__ P1, const float* __restrict__ P2,
                              _Float16* __restrict__ Wfrag, _Float16* __restrict__ Pfrag,
                              _Float16* __restrict__ xF)
{
    size_t idx = (size_t)blockIdx.x * 256 + threadIdx.x;
    if (idx < WF_HALFS) {
        int slab = (int)(idx >> 17);
        int l = slab / 12, ht = slab % 12;
        int r = (int)(idx & 131071);
        int kc = r >> 12;
        int wvp = (r >> 9) & 7;
        int u = r & 511;
        int lane = u >> 3, e = u & 7;
        int g = wvp >> 1, hh = wvp & 1;
        int col = g * Hdim + ht * 64 + hh * 32 + (lane & 31);
        int a = kc * 16 + (lane >> 5) * 8 + e;
        float v = 0.0f;
        if (l == 0) {
            if (a < 256)      v = W0[(size_t)(40 + a) * 3072 + col];
            else if (a < 296) v = W0[(size_t)(a - 256) * 3072 + col];
        } else if (a < 512) {
            const float* W = (l == 1) ? W1 : W2;
            v = W[(size_t)a * 3072 + col];
        }
        Wfrag[idx] = (_Float16)v;
    } else if (idx < WF_HALFS + PF_HALFS) {
        size_t i = idx - WF_HALFS;
        int l = (int)(i / 196608);
        int r = (int)(i % 196608);
        int cq = r / 49152;
        int r2 = r % 49152;
        int kc = r2 / 1024;
        int cgp = (r2 >> 9) & 1;
        int u = r2 & 511;
        int lane = u >> 3, e = u & 7;
        int pj = cq * 64 + cgp * 32 + (lane & 31);
        int k = kc * 16 + (lane >> 5) * 8 + e;
        const float* P = (l == 0) ? P0 : (l == 1) ? P1 : P2;
        Pfrag[i] = (_Float16)P[(size_t)k * PJdim + pj];
    } else if (idx < WF_HALFS + PF_HALFS + XF_HALFS) {
        size_t i = idx - WF_HALFS - PF_HALFS;
        int t = (int)(i / 40960);
        int r = (int)(i % 40960);
        int bt2 = r / 8192;
        int r2 = r % 8192;
        int kcx = r2 / 2048;
        int rt = (r2 >> 9) & 3;
        int u = r2 & 511;
        int lane = u >> 3, e = u & 7;
        int row = bt2 * 128 + rt * 32 + (lane & 31);
        int xcol = kcx * 16 + (lane >> 5) * 8 + e;
        float v = (xcol < 40) ? x[((size_t)t * Bdim + row) * 40 + xcol] : 0.0f;
        xF[i] = (_Float16)v;
    }
}

// ---------------- granule-staged GEMM cores ----------------
template <int G>
__device__ __forceinline__ void gate_gemm(const uint4* const (&gs)[8], const half8 (&Breg)[32],
                                          floatx16 (&acc)[4], _Float16* Abuf, int tid, int lane)
{
    {
        uint4 v0 = gs[0][tid], v1 = gs[0][tid + 512];
        uint4* d = (uint4*)Abuf;
        d[tid] = v0; d[tid + 512] = v1;
        __syncthreads();
    }
#pragma unroll
    for (int g = 0; g < G; ++g) {
        uint4 p0, p1;
        const bool pf = (g + 1 < G);
        if (pf) { p0 = gs[g + 1][tid]; p1 = gs[g + 1][tid + 512]; }
        const _Float16* base = Abuf + (g & 1) * 8192;
#pragma unroll
        for (int c4 = 0; c4 < 4; ++c4) {
#pragma unroll
            for (int rt = 0; rt < 4; ++rt) {
                half8 a = *(const half8*)(base + (c4 * 4 + rt) * 512 + lane * 8);
                acc[rt] = __builtin_amdgcn_mfma_f32_32x32x16_f16(a, Breg[g * 4 + c4], acc[rt], 0, 0, 0);
            }
        }
        if (pf) {
            uint4* d = (uint4*)(Abuf + ((g + 1) & 1) * 8192);
            d[tid] = p0; d[tid + 512] = p1;
        }
        __syncthreads();
    }
}

__device__ __forceinline__ void proj_gemm(const uint4* const (&gs)[12], const half8 (&Preg)[48],
                                          floatx16& pacc, _Float16* Abuf, int tid, int lane, int rh)
{
    {
        uint4 v0 = gs[0][tid], v1 = gs[0][tid + 512];
        uint4* d = (uint4*)Abuf;
        d[tid] = v0; d[tid + 512] = v1;
        __syncthreads();
    }
#pragma unroll
    for (int g = 0; g < 12; ++g) {
        uint4 p0, p1;
        const bool pf = (g + 1 < 12);
        if (pf) { p0 = gs[g + 1][tid]; p1 = gs[g + 1][tid + 512]; }
        const _Float16* base = Abuf + (g & 1) * 8192;
#pragma unroll
        for (int c4 = 0; c4 < 4; ++c4) {
            half8 a = *(const half8*)(base + (c4 * 4 + rh) * 512 + lane * 8);
            pacc = __builtin_amdgcn_mfma_f32_32x32x16_f16(a, Preg[g * 4 + c4], pacc, 0, 0, 0);
        }
        if (pf) {
            uint4* d = (uint4*)(Abuf + ((g + 1) & 1) * 8192);
            d[tid] = p0; d[tid + 512] = p1;
        }
        __syncthreads();
    }
}

// ---------------- one gate cell-step ----------------
__device__ __forceinline__ void gate_run(int l,
                                         const _Float16* __restrict__ hOwnSlab,
                                         const _Float16* __restrict__ hBelSlab,
                                         const _Float16* __restrict__ xGran,
                                         _Float16* __restrict__ mslab,
                                         const half8 (&Breg)[32], float bv, float (&c)[8][2],
                                         char* smem, int tid)
{
    const int wv = tid >> 6, lane = tid & 63;
    const int g = wv >> 1, hh = wv & 1;
    _Float16* Abuf = (_Float16*)smem;

    floatx16 acc[4];
#pragma unroll
    for (int rt = 0; rt < 4; ++rt)
#pragma unroll
        for (int e = 0; e < 16; ++e) acc[rt][e] = 0.f;

    const uint4* gs[8];
    if (l == 0) {
#pragma unroll
        for (int g2 = 0; g2 < 4; ++g2) gs[g2] = (const uint4*)(hOwnSlab + g2 * 8192);
        gs[4] = (const uint4*)xGran;
        gs[5] = gs[6] = gs[7] = gs[4];
        gate_gemm<5>(gs, Breg, acc, Abuf, tid, lane);
    } else {
#pragma unroll
        for (int g2 = 0; g2 < 4; ++g2) {
            gs[g2] = (const uint4*)(hBelSlab + g2 * 8192);
            gs[4 + g2] = (const uint4*)(hOwnSlab + g2 * 8192);
        }
        gate_gemm<8>(gs, Breg, acc, Abuf, tid, lane);
    }

    // elementwise via LDS (aliases dead Abuf), c in VGPRs
    float* zst = (float*)smem;
    _Float16* Mlds = (_Float16*)(smem + 16384);
    const int gcol = g * 64 + hh * 32 + (lane & 31);
    const int trow = tid >> 5, uu = tid & 31, hc0 = 2 * uu;
#pragma unroll
    for (int p = 0; p < 8; ++p) {
#pragma unroll
        for (int rr = 0; rr < 8; ++rr) {
            int r16 = (rr & 3) + ((rr >> 2) << 3) + ((lane >> 5) << 2);
            zst[r16 * 256 + gcol] = acc[p >> 1][(p & 1) * 8 + rr] + bv;
        }
        __syncthreads();
        unsigned pk = 0;
#pragma unroll
        for (int jj = 0; jj < 2; ++jj) {
            int hc = hc0 + jj;
            float zi = zst[trow * 256 + hc];
            float zj = zst[trow * 256 + 64 + hc];
            float zf = zst[trow * 256 + 128 + hc];
            float zo = zst[trow * 256 + 192 + hc];
            float cn = sigm(zf) * c[p][jj] + sigm(zi) * tanh_fast(zj);
            c[p][jj] = cn;
            _Float16 mh = (_Float16)(sigm(zo) * tanh_fast(cn));
            unsigned short us = *(unsigned short*)&mh;
            pk |= ((unsigned)us) << (16 * jj);
        }
        {
            int f = (p >> 1) * 4 + (hc0 >> 4);
            int lane32 = (p & 1) * 16 + trow + 32 * ((hc0 >> 3) & 1);
            *(unsigned*)(Mlds + f * 512 + lane32 * 8 + (hc0 & 7)) = pk;
        }
        __syncthreads();
    }
    // coalesced flush: Mlds -> mbufF (frag order)
    {
        int f = tid >> 5, o = (tid & 31) * 16;
        uint4 w0 = *(const uint4*)(Mlds + f * 512 + o);
        uint4 w1 = *(const uint4*)(Mlds + f * 512 + o + 8);
        _Float16* dst = mslab + (size_t)(f & 3) * 2048 + (f >> 2) * 512 + o;
        *(uint4*)dst = w0;
        *(uint4*)(dst + 8) = w1;
    }
}

// ---------------- one proj step ----------------
__device__ __forceinline__ void proj_run(const _Float16* __restrict__ mslice,
                                         _Float16* __restrict__ hdstBase,
                                         const half8 (&Preg)[48], char* smem, int tid)
{
    const int wv = tid >> 6, lane = tid & 63;
    const int rh = wv >> 1, cgp = wv & 1;
    _Float16* Abuf = (_Float16*)smem;

    floatx16 pacc;
#pragma unroll
    for (int e = 0; e < 16; ++e) pacc[e] = 0.f;

    const uint4* gs[12];
#pragma unroll
    for (int g2 = 0; g2 < 12; ++g2) gs[g2] = (const uint4*)(mslice + g2 * 8192);
    proj_gemm(gs, Preg, pacc, Abuf, tid, lane, rh);

    _Float16* Hlds = (_Float16*)smem;
    const int col32 = lane & 31;
    const int fH = (cgp * 2 + (col32 >> 4)) * 4 + rh;
    const int lane32 = 32 * ((col32 >> 3) & 1);
    const int e0 = col32 & 7;
#pragma unroll
    for (int q = 0; q < 4; ++q)
#pragma unroll
        for (int i = 0; i < 4; ++i) {
            int row32 = i + 8 * q + 4 * (lane >> 5);
            Hlds[fH * 512 + (row32 + lane32) * 8 + e0] = (_Float16)pacc[q * 4 + i];
        }
    __syncthreads();
    {
        int f = tid >> 5, o = (tid & 31) * 16;
        uint4 w0 = *(const uint4*)(Hlds + f * 512 + o);
        uint4 w1 = *(const uint4*)(Hlds + f * 512 + o + 8);
        _Float16* dst = hdstBase + (size_t)(f >> 2) * 2048 + (f & 3) * 512 + o;
        *(uint4*)dst = w0;
        *(uint4*)(dst + 8) = w1;
    }
    __syncthreads();   // drains vmcnt -> producer may signal right after return
}

__device__ __forceinline__ void finalize_row(const _Float16* __restrict__ hPar1,
                                             float* __restrict__ out, int row, int lane)
{
    int bt2 = row >> 7, rt = (row >> 5) & 3, r32 = row & 31;
    int kcH = lane >> 2;
    int l32 = r32 + 32 * ((lane >> 1) & 1);
    int e0 = (lane & 1) * 4;
    const _Float16* p = hPar1 + ((((size_t)10 + bt2) * 16 + kcH) * 4 + rt) * 512 + l32 * 8 + e0;
    float v0 = (float)p[0], v1 = (float)p[1], v2 = (float)p[2], v3 = (float)p[3];
    float ss = v0 * v0 + v1 * v1 + v2 * v2 + v3 * v3;
#pragma unroll
    for (int o = 32; o > 0; o >>= 1) ss += __shfl_xor(ss, o, 64);
    float rs = rsqrtf(fmaxf(ss, 1e-12f));
    float4 o4;
    o4.x = v0 * rs; o4.y = v1 * rs; o4.z = v2 * rs; o4.w = v3 * rs;
    *(float4*)(out + (size_t)row * PJdim + lane * 4) = o4;
}

// ---------------- persistent dataflow kernel (no grid.sync) ----------------
__global__ __launch_bounds__(512, 1)
void lstm_persist(const _Float16* __restrict__ xF, const _Float16* __restrict__ Wfrag,
                  const _Float16* __restrict__ Pfrag,
                  const float* __restrict__ bias0, const float* __restrict__ bias1,
                  const float* __restrict__ bias2,
                  _Float16* __restrict__ hF, _Float16* __restrict__ mbufF,
                  int* __restrict__ cnt, float* __restrict__ out)
{
    __shared__ __align__(16) char smem[32768];
    const int tid = threadIdx.x, bid = blockIdx.x;
    const int wv = tid >> 6, lane = tid & 63;
    const int xc = bid & 7, j = bid >> 3;

    int role = 0, l = 0, ht = 0, bt2 = 0, cq = 0;
    if (j < 24) {
        int grp = xc + 8 * (j / 12);
        if (grp < 15) { role = 1; l = grp / 5; bt2 = grp % 5; ht = j % 12; }
    } else {
        int grp = (j < 28) ? xc : xc + 8;
        if (grp < 15) { role = 2; l = grp / 5; bt2 = grp % 5; cq = (j < 28) ? (j - 24) : (j - 28); }
    }
    const int slot = l * 5 + bt2;

    if (role == 1) {
        half8 Breg[32];
        const _Float16* wslab = Wfrag + (size_t)(l * 12 + ht) * 131072;
        const int nkc = (l == 0) ? 20 : 32;
#pragma unroll
        for (int kc = 0; kc < 32; ++kc)
            if (kc < nkc) Breg[kc] = *(const half8*)(wslab + (kc * 8 + wv) * 512 + lane * 8);
        const float* bias = (l == 0) ? bias0 : (l == 1) ? bias1 : bias2;
        const int g = wv >> 1, hh = wv & 1;
        const float bv = bias[g * Hdim + ht * 64 + hh * 32 + (lane & 31)] + ((g == 2) ? 1.0f : 0.0f);
        float c[8][2];
#pragma unroll
        for (int p = 0; p < 8; ++p) { c[p][0] = 0.f; c[p][1] = 0.f; }

        int* mC = cnt + ((size_t)slot * 12 + ht) * 16;
        const _Float16* hOwnSlabs = hF;
        for (int t = 0; t < Tdim; ++t) {
            if (tid == 0) {
                // h(l,t-1) ready: each proj(l,cq) finished iteration t-1
                if (t > 0)
                    for (int q = 0; q < 4; ++q) waitGE(cnt + (180 + (size_t)slot * 4 + q) * 16, t);
                // h(l-1,t) ready: each proj(l-1,cq) finished iteration t
                if (l > 0)
                    for (int q = 0; q < 4; ++q) waitGE(cnt + (180 + (size_t)(slot - 5) * 4 + q) * 16, t + 1);
            }
            __syncthreads();
            const _Float16* hOwn = hOwnSlabs + (size_t)((t + 1) & 1) * HFP + (size_t)slot * 32768;
            const _Float16* hBel = (l > 0) ? hOwnSlabs + (size_t)(t & 1) * HFP + (size_t)(slot - 5) * 32768
                                           : nullptr;
            const _Float16* xG = xF + ((size_t)t * 5 + bt2) * 8192;
            _Float16* mslab = mbufF + (size_t)(t & 1) * MBP + ((size_t)slot * 48 + ht * 4) * 2048;
            gate_run(l, hOwn, hBel, xG, mslab, Breg, bv, c, smem, tid);
            __syncthreads();              // drain m stores (vmcnt) before release
            if (tid == 0) signal1(mC);
        }
    } else if (role == 2) {
        half8 Preg[48];
        const _Float16* pslab = Pfrag + ((size_t)l * 4 + cq) * 49152;
#pragma unroll
        for (int kc = 0; kc < 48; ++kc)
            Preg[kc] = *(const half8*)(pslab + (kc * 2 + (wv & 1)) * 512 + lane * 8);

        int* pC = cnt + (180 + (size_t)slot * 4 + cq) * 16;
        for (int t = 0; t < Tdim; ++t) {
            if (tid == 0) {
                // m(l,t) ready: each gate(l,ht) finished iteration t
                for (int h2 = 0; h2 < 12; ++h2) waitGE(cnt + ((size_t)slot * 12 + h2) * 16, t + 1);
                // h-parity overwrite safe: gate(l+1,*) finished iteration t-2
                if (l < 2 && t >= 2)
                    for (int h2 = 0; h2 < 12; ++h2) waitGE(cnt + ((size_t)(slot + 5) * 12 + h2) * 16, t - 1);
            }
            __syncthreads();
            const _Float16* mslice = mbufF + (size_t)(t & 1) * MBP + (size_t)slot * 98304;
            _Float16* hdst = hF + (size_t)(t & 1) * HFP + ((size_t)slot * 16 + cq * 4) * 2048;
            proj_run(mslice, hdst, Preg, smem, tid);
            if (tid == 0) signal1(pC);
        }
        if (l == 2) {
            if (tid == 0)
                for (int q = 0; q < 4; ++q) waitGE(cnt + (180 + (size_t)slot * 4 + q) * 16, Tdim);
            __syncthreads();
#pragma unroll
            for (int i = 0; i < 4; ++i)
                finalize_row(hF + HFP, out, bt2 * 128 + cq * 32 + wv * 4 + i, lane);
        }
    }
}

// ---------------- fallback path: per-step kernels, c in global ----------------
__global__ __launch_bounds__(512, 1)
void gate_fb(const _Float16* __restrict__ xF, const _Float16* __restrict__ Wfrag,
             const float* __restrict__ bias0, const float* __restrict__ bias1,
             const float* __restrict__ bias2,
             _Float16* __restrict__ hF, _Float16* __restrict__ mbufF,
             float* __restrict__ cfb, int s)
{
    __shared__ __align__(16) char smem[32768];
    const int tid = threadIdx.x, bid = blockIdx.x;
    const int l = bid / 60, r = bid % 60, ht = r / 12 == 0 ? r % 12 : r % 12, bt2 = r / 12;
    const int t = s - l;
    if (t < 0 || t >= Tdim) return;
    const int wv = tid >> 6, lane = tid & 63;
    const int slot = l * 5 + bt2;
    half8 Breg[32];
    const _Float16* wslab = Wfrag + (size_t)(l * 12 + ht) * 131072;
    const int nkc = (l == 0) ? 20 : 32;
#pragma unroll
    for (int kc = 0; kc < 32; ++kc)
        if (kc < nkc) Breg[kc] = *(const half8*)(wslab + (kc * 8 + wv) * 512 + lane * 8);
    const float* bias = (l == 0) ? bias0 : (l == 1) ? bias1 : bias2;
    const int g = wv >> 1, hh = wv & 1;
    const float bv = bias[g * Hdim + ht * 64 + hh * 32 + (lane & 31)] + ((g == 2) ? 1.0f : 0.0f);
    float c[8][2];
    size_t cb = ((size_t)bid * 512 + tid) * 16;
#pragma unroll
    for (int p = 0; p < 8; ++p) { c[p][0] = cfb[cb + p * 2]; c[p][1] = cfb[cb + p * 2 + 1]; }
    const _Float16* hOwn = hF + (size_t)((t + 1) & 1) * HFP + (size_t)slot * 32768;
    const _Float16* hBel = (l > 0) ? hF + (size_t)(t & 1) * HFP + (size_t)(slot - 5) * 32768 : nullptr;
    const _Float16* xG = xF + ((size_t)t * 5 + bt2) * 8192;
    _Float16* mslab = mbufF + (size_t)(t & 1) * MBP + ((size_t)slot * 48 + ht * 4) * 2048;
    gate_run(l, hOwn, hBel, xG, mslab, Breg, bv, c, smem, tid);
#pragma unroll
    for (int p = 0; p < 8; ++p) { cfb[cb + p * 2] = c[p][0]; cfb[cb + p * 2 + 1] = c[p][1]; }
}

__global__ __launch_bounds__(512, 1)
void proj_fb(const _Float16* __restrict__ Pfrag, const _Float16* __restrict__ mbufF,
             _Float16* __restrict__ hF, int s)
{
    __shared__ __align__(16) char smem[32768];
    const int tid = threadIdx.x, bid = blockIdx.x;
    const int l = bid / 20, r = bid % 20, cq = r / 5, bt2 = r % 5;
    const int t = s - l;
    if (t < 0 || t >= Tdim) return;
    const int wv = tid >> 6, lane = tid & 63;
    const int slot = l * 5 + bt2;
    half8 Preg[48];
    const _Float16* pslab = Pfrag + ((size_t)l * 4 + cq) * 49152;
#pragma unroll
    for (int kc = 0; kc < 48; ++kc)
        Preg[kc] = *(const half8*)(pslab + (kc * 2 + (wv & 1)) * 512 + lane * 8);
    const _Float16* mslice = mbufF + (size_t)(t & 1) * MBP + (size_t)slot * 98304;
    _Float16* hdst = hF + (size_t)(t & 1) * HFP + ((size_t)slot * 16 + cq * 4) * 2048;
    proj_run(mslice, hdst, Preg, smem, tid);
}

__global__ __launch_bounds__(512, 1)
void fin_fb(const _Float16* __restrict__ hF, float* __restrict__ out)
{
    finalize_row(hF + HFP, out, blockIdx.x * 8 + (threadIdx.x >> 6), threadIdx.x & 63);
}

extern "C" void kernel_launch(void* const* d_in, const int* in_sizes, int n_in,
                              void* d_out, int out_size, void* d_ws, size_t ws_size,
                              hipStream_t stream)
{
    (void)in_sizes; (void)n_in; (void)out_size; (void)ws_size;
    const float* x  = (const float*)d_in[0];
    const float* W0 = (const float*)d_in[1];
    const float* b0 = (const float*)d_in[2];
    const float* P0 = (const float*)d_in[3];
    const float* W1 = (const float*)d_in[4];
    const float* b1 = (const float*)d_in[5];
    const float* P1 = (const float*)d_in[6];
    const float* W2 = (const float*)d_in[7];
    const float* b2 = (const float*)d_in[8];
    const float* P2 = (const float*)d_in[9];

    char* ws = (char*)d_ws;
    int*      cnt   = (int*)(ws + CNT_OFF);
    _Float16* hF    = (_Float16*)(ws + HF_OFF);
    _Float16* mbufF = (_Float16*)(ws + MB_OFF);
    _Float16* xF    = (_Float16*)(ws + XF_OFF);
    _Float16* Wfrag = (_Float16*)(ws + WF_OFF);
    _Float16* Pfrag = (_Float16*)(ws + PF_OFF);
    float*    cfb   = (float*)(ws + CFB_OFF);
    float*    outp  = (float*)d_out;

    // zero counters + both hF parities (+ fallback c)
    hipMemsetAsync(ws, 0, HF_OFF + 2ull * HFP * 2, stream);
    hipMemsetAsync(cfb, 0, CFB_BYTES, stream);

    {
        constexpr size_t total = WF_HALFS + PF_HALFS + XF_HALFS;
        int grid = (int)((total + 255) / 256);
        repack_kernel<<<grid, 256, 0, stream>>>(x, W0, W1, W2, P0, P1, P2, Wfrag, Pfrag, xF);
    }

    int occ = 0;
    hipError_t oe = hipOccupancyMaxActiveBlocksPerMultiprocessor(&occ, lstm_persist, 512, 0);
    bool coop = (oe == hipSuccess && occ >= 1);
    if (coop) {
        void* args[] = { (void*)&xF, (void*)&Wfrag, (void*)&Pfrag,
                         (void*)&b0, (void*)&b1, (void*)&b2,
                         (void*)&hF, (void*)&mbufF, (void*)&cnt, (void*)&outp };
        hipError_t le = hipLaunchCooperativeKernel((const void*)lstm_persist,
                                                   dim3(256), dim3(512), args, 0, stream);
        if (le != hipSuccess) { (void)hipGetLastError(); coop = false; }
    }
    if (!coop) {
        for (int s = 0; s < NSTEP; ++s) {
            gate_fb<<<180, 512, 0, stream>>>(xF, Wfrag, b0, b1, b2, hF, mbufF, cfb, s);
            proj_fb<<<60, 512, 0, stream>>>(Pfrag, mbufF, hF, s);
        }
        fin_fb<<<80, 512, 0, stream>>>(hF, outp);
    }
}